// Round 8
// baseline (563.683 us; speedup 1.0000x reference)
//
#include <hip/hip_runtime.h>

#define B_   4
#define S_   2048
#define D_   1024
#define DFF_ 4096

typedef __attribute__((ext_vector_type(8))) short short8;
typedef __attribute__((ext_vector_type(4))) float floatx4;

__device__ __forceinline__ unsigned short f2b(float f) {
    unsigned int u = __float_as_uint(f);
    unsigned int r = (u + 0x7fffu + ((u >> 16) & 1u)) >> 16;
    return (unsigned short)r;
}
__device__ __forceinline__ float b2f(unsigned short u) {
    return __uint_as_float((unsigned int)u << 16);
}

// XCD-aware swizzle: blocks sharing an A row-tile (same by) land on one XCD.
__device__ __forceinline__ void swizzle_xy(int gx, int gy, int& bx, int& by) {
    if ((gy & 7) == 0) {
        const int linear = by * gx + bx;
        const int xcd = linear & 7;
        const int slot = linear >> 3;
        const int r = slot / gx;
        by = xcd * (gy >> 3) + r;
        bx = slot - r * gx;
    }
}

// ---------------------------------------------------------------------------
// GEMM core: 256x128 tile, BK=64, 512 threads / 8 waves (each 64x64).
// 2-barrier K-loop. XOR swizzle g ^ (r&7) -> conflict-free b128 frag reads.
// ---------------------------------------------------------------------------
__device__ __forceinline__ void gemm_core256(
    const unsigned short* __restrict__ A,
    const unsigned short* __restrict__ Bt,
    int ldA, int ldB, int K, int m0, int n0,
    unsigned short* As, unsigned short* Bs,
    floatx4 acc[4][4])
{
    const int tid  = threadIdx.x;   // 0..511
    const int lane = tid & 63;
    const int wave = tid >> 6;      // 0..7

    const int ra = tid >> 3;        // 0..63 (row within pass)
    const int pg = tid & 7;         // physical k-group
    const int cg = (pg ^ (ra & 7)) * 8;   // logical k-group loaded
    const unsigned short* gA = A  + (long long)(m0 + ra) * ldA + cg;
    const unsigned short* gB = Bt + (long long)(n0 + ra) * ldB + cg;
    const long long pA = 64LL * ldA;
    const long long pB = 64LL * ldB;

    unsigned short* dA = As + wave * 512;
    unsigned short* dB = Bs + wave * 512;

    const int wr = (wave >> 1) * 64;  // 0..192
    const int wc = (wave & 1) * 64;   // 0 or 64
    const int fr = lane & 15;
    const int q  = lane >> 4;

    int aoff[2][4], boff[2][4];
#pragma unroll
    for (int h = 0; h < 2; h++)
#pragma unroll
        for (int i = 0; i < 4; i++) {
            const int rA = wr + i * 16 + fr;
            const int rB = wc + i * 16 + fr;
            const int g  = h * 4 + q;
            aoff[h][i] = rA * 64 + ((g ^ (rA & 7)) * 8);
            boff[h][i] = rB * 64 + ((g ^ (rB & 7)) * 8);
        }

    for (int k0 = 0; k0 < K; k0 += 64) {
        __syncthreads();
#pragma unroll
        for (int p = 0; p < 4; p++)
            __builtin_amdgcn_global_load_lds(
                (const __attribute__((address_space(1))) void*)(gA + k0 + p * pA),
                (__attribute__((address_space(3))) void*)(dA + p * 4096), 16, 0, 0);
#pragma unroll
        for (int p = 0; p < 2; p++)
            __builtin_amdgcn_global_load_lds(
                (const __attribute__((address_space(1))) void*)(gB + k0 + p * pB),
                (__attribute__((address_space(3))) void*)(dB + p * 4096), 16, 0, 0);
        __syncthreads();

#pragma unroll
        for (int h = 0; h < 2; h++) {
            short8 af[4], bfr[4];
#pragma unroll
            for (int mi = 0; mi < 4; mi++) af[mi] = *(const short8*)&As[aoff[h][mi]];
#pragma unroll
            for (int ni = 0; ni < 4; ni++) bfr[ni] = *(const short8*)&Bs[boff[h][ni]];
#pragma unroll
            for (int mi = 0; mi < 4; mi++)
#pragma unroll
                for (int ni = 0; ni < 4; ni++)
                    acc[mi][ni] = __builtin_amdgcn_mfma_f32_16x16x32_bf16(
                        af[mi], bfr[ni], acc[mi][ni], 0, 0, 0);
        }
    }
}

// ---------------------------------------------------------------------------
__global__ __launch_bounds__(256) void cast_bf16_kernel(
    const float4* __restrict__ src, ushort4* __restrict__ dst, int n4)
{
    int i = blockIdx.x * 256 + threadIdx.x;
    if (i < n4) {
        float4 f = src[i];
        ushort4 u;
        u.x = f2b(f.x); u.y = f2b(f.y); u.z = f2b(f.z); u.w = f2b(f.w);
        dst[i] = u;
    }
}

// ---------------------------------------------------------------------------
// Batched transpose+cast of all six weight matrices in one launch.
// tiles: [0,4096)   = Wq,Wk,Wv,Wo (1024x1024, 1024 tiles each)
//        [4096,8192)= W1 (1024x4096)
//        [8192,12288)=W2 (4096x1024)
// ---------------------------------------------------------------------------
__device__ __forceinline__ void trans_tile(
    const float* __restrict__ W, unsigned short* __restrict__ Wt,
    int K, int N, int bx, int by, int tx, int ty)
{
    __shared__ float tile[32][33];
#pragma unroll
    for (int j = 0; j < 32; j += 8)
        tile[ty + j][tx] = W[(long long)(by * 32 + ty + j) * N + bx * 32 + tx];
    __syncthreads();
#pragma unroll
    for (int j = 0; j < 32; j += 8)
        Wt[(long long)(bx * 32 + ty + j) * K + by * 32 + tx] = f2b(tile[tx][ty + j]);
}

__global__ __launch_bounds__(256) void transpose_all_kernel(
    const float* __restrict__ Wq, const float* __restrict__ Wk,
    const float* __restrict__ Wv, const float* __restrict__ Wo,
    const float* __restrict__ W1, const float* __restrict__ W2,
    unsigned short* __restrict__ Wqkv, unsigned short* __restrict__ Wot,
    unsigned short* __restrict__ W1t, unsigned short* __restrict__ W2t)
{
    const int id = blockIdx.x;
    const int tx = threadIdx.x & 31;
    const int ty = threadIdx.x >> 5;
    if (id < 4096) {
        const int m = id >> 10;          // 0..3
        const int t = id & 1023;
        const int bx = t & 31, by = t >> 5;
        const float* src = (m == 0) ? Wq : (m == 1) ? Wk : (m == 2) ? Wv : Wo;
        unsigned short* dst = (m == 3) ? Wot : (Wqkv + (long long)m * 1024 * 1024);
        trans_tile(src, dst, 1024, 1024, bx, by, tx, ty);
    } else if (id < 8192) {
        const int t = id - 4096;
        const int bx = t & 127, by = t >> 7;   // N=4096 -> 128 x tiles
        trans_tile(W1, W1t, 1024, 4096, bx, by, tx, ty);
    } else {
        const int t = id - 8192;
        const int bx = t & 31, by = t >> 5;    // N=1024, K=4096
        trans_tile(W2, W2t, 4096, 1024, bx, by, tx, ty);
    }
}

// ---------------------------------------------------------------------------
// bf16 transpose: Vb [B][S][D] -> Vt [B][D][S]. 64x64 LDS tiles, ushort4 IO.
// ---------------------------------------------------------------------------
__global__ __launch_bounds__(256) void vtrans_kernel(
    const unsigned short* __restrict__ Vb, unsigned short* __restrict__ Vt)
{
    __shared__ unsigned short tile[64][68];
    const int b  = blockIdx.z;
    const int s0 = blockIdx.y * 64;
    const int d0 = blockIdx.x * 64;
    const int tx = threadIdx.x & 15;
    const int ty = threadIdx.x >> 4;

    const unsigned short* src = Vb + ((long long)b * S_ + s0) * D_ + d0;
#pragma unroll
    for (int j = 0; j < 4; j++) {
        const int s = j * 16 + ty;
        ushort4 v = *(const ushort4*)(src + (long long)s * D_ + tx * 4);
        tile[tx * 4 + 0][s] = v.x;
        tile[tx * 4 + 1][s] = v.y;
        tile[tx * 4 + 2][s] = v.z;
        tile[tx * 4 + 3][s] = v.w;
    }
    __syncthreads();
    unsigned short* dst = Vt + ((long long)b * D_ + d0) * S_ + s0;
#pragma unroll
    for (int j = 0; j < 4; j++) {
        const int d = j * 16 + ty;
        ushort4 v;
        v.x = tile[d][tx * 4 + 0];
        v.y = tile[d][tx * 4 + 1];
        v.z = tile[d][tx * 4 + 2];
        v.w = tile[d][tx * 4 + 3];
        *(ushort4*)(dst + (long long)d * S_ + tx * 4) = v;
    }
}

// ---------------------------------------------------------------------------
// GEMM: C = act(scale * A @ Bt^T + bias), batched via z. 256x128 tile.
// ---------------------------------------------------------------------------
template <int OUT_BF16, int ACT_LEAKY, int HAS_BIAS>
__global__ __launch_bounds__(512, 4) void gemm_bt(
    const unsigned short* __restrict__ A,
    const unsigned short* __restrict__ Bt,
    void* __restrict__ Cptr,
    const float* __restrict__ bias,
    int M, int N, int K, float scale,
    long long sA, long long sB, long long sC)
{
    __shared__ unsigned short As[256 * 64];
    __shared__ unsigned short Bs[128 * 64];

    const int lane = threadIdx.x & 63;
    const int wave = threadIdx.x >> 6;
    const int z    = blockIdx.z;

    int bx = blockIdx.x, by = blockIdx.y;
    swizzle_xy(gridDim.x, gridDim.y, bx, by);
    const int m0 = by * 256;
    const int n0 = bx * 128;

    floatx4 acc[4][4];
#pragma unroll
    for (int i = 0; i < 4; i++)
#pragma unroll
        for (int j = 0; j < 4; j++) acc[i][j] = floatx4{0.f, 0.f, 0.f, 0.f};

    gemm_core256(A + (long long)z * sA, Bt + (long long)z * sB,
                 K, K, K, m0, n0, As, Bs, acc);

    const int wr = (wave >> 1) * 64;
    const int wc = (wave & 1) * 64;
    const int cr = (lane >> 4) * 4;
    const int cc = lane & 15;
    float* Cf = (float*)Cptr;
    unsigned short* Cb = (unsigned short*)Cptr;

#pragma unroll
    for (int mi = 0; mi < 4; mi++) {
#pragma unroll
        for (int ni = 0; ni < 4; ni++) {
            const int col = n0 + wc + ni * 16 + cc;
            const float bv = HAS_BIAS ? bias[col] : 0.0f;
#pragma unroll
            for (int r = 0; r < 4; r++) {
                const int row = m0 + wr + mi * 16 + cr + r;
                float v = acc[mi][ni][r] * scale + bv;
                if (ACT_LEAKY) v = (v > 0.0f) ? v : 0.01f * v;
                const long long idx = (long long)z * sC + (long long)row * N + col;
                if (OUT_BF16) Cb[idx] = f2b(v); else Cf[idx] = v;
            }
        }
    }
}

// ---------------------------------------------------------------------------
// Split-K GEMM, 256x128 tile: blockIdx.z = b * NK + ks;
// partial P[(ks*nb + b)][M][N] stored bf16.
// ---------------------------------------------------------------------------
template <int NK>
__global__ __launch_bounds__(512, 4) void gemm_bt_sk(
    const unsigned short* __restrict__ A,
    const unsigned short* __restrict__ Bt,
    unsigned short* __restrict__ P,
    int M, int N, int Kslice, int ldA, int ldB,
    long long sA, long long sB)
{
    __shared__ unsigned short As[256 * 64];
    __shared__ unsigned short Bs[128 * 64];

    const int lane = threadIdx.x & 63;
    const int wave = threadIdx.x >> 6;
    const int z    = blockIdx.z;
    const int ks   = z % NK;
    const int b    = z / NK;
    const int nb   = gridDim.z / NK;

    int bx = blockIdx.x, by = blockIdx.y;
    swizzle_xy(gridDim.x, gridDim.y, bx, by);
    const int m0 = by * 256;
    const int n0 = bx * 128;

    floatx4 acc[4][4];
#pragma unroll
    for (int i = 0; i < 4; i++)
#pragma unroll
        for (int j = 0; j < 4; j++) acc[i][j] = floatx4{0.f, 0.f, 0.f, 0.f};

    gemm_core256(A + (long long)b * sA + (long long)ks * Kslice,
                 Bt + (long long)b * sB + (long long)ks * Kslice,
                 ldA, ldB, Kslice, m0, n0, As, Bs, acc);

    const long long pbase = ((long long)ks * nb + b) * (long long)M * N;

    const int wr = (wave >> 1) * 64;
    const int wc = (wave & 1) * 64;
    const int cr = (lane >> 4) * 4;
    const int cc = lane & 15;

#pragma unroll
    for (int mi = 0; mi < 4; mi++) {
#pragma unroll
        for (int ni = 0; ni < 4; ni++) {
            const int col = n0 + wc + ni * 16 + cc;
#pragma unroll
            for (int r = 0; r < 4; r++) {
                const int row = m0 + wr + mi * 16 + cr + r;
                P[pbase + (long long)row * N + col] = f2b(acc[mi][ni][r]);
            }
        }
    }
}

// ---------------------------------------------------------------------------
// Fused QKV GEMM, 256x128 tile: A[8192,1024] @ Wqkvt[3072,1024]^T
// All three segments write coalesced [row][c]; V transposed separately.
// ---------------------------------------------------------------------------
__global__ __launch_bounds__(512, 4) void gemm_qkv(
    const unsigned short* __restrict__ A,
    const unsigned short* __restrict__ Bt,
    unsigned short* __restrict__ Qb,
    unsigned short* __restrict__ Kb,
    unsigned short* __restrict__ Vb,
    const float* __restrict__ bq,
    const float* __restrict__ bk,
    const float* __restrict__ bv)
{
    __shared__ unsigned short As[256 * 64];
    __shared__ unsigned short Bs[128 * 64];

    const int lane = threadIdx.x & 63;
    const int wave = threadIdx.x >> 6;

    int bx = blockIdx.x, by = blockIdx.y;
    swizzle_xy(gridDim.x, gridDim.y, bx, by);
    const int m0 = by * 256;
    const int n0 = bx * 128;

    floatx4 acc[4][4];
#pragma unroll
    for (int i = 0; i < 4; i++)
#pragma unroll
        for (int j = 0; j < 4; j++) acc[i][j] = floatx4{0.f, 0.f, 0.f, 0.f};

    gemm_core256(A, Bt, D_, D_, D_, m0, n0, As, Bs, acc);

    const int wr = (wave >> 1) * 64;
    const int wc = (wave & 1) * 64;
    const int cr = (lane >> 4) * 4;
    const int cc = lane & 15;

#pragma unroll
    for (int mi = 0; mi < 4; mi++) {
#pragma unroll
        for (int ni = 0; ni < 4; ni++) {
            const int col = n0 + wc + ni * 16 + cc;
            const int seg = col >> 10;
            const int c = col & 1023;
            const float* bp = (seg == 0) ? bq : ((seg == 1) ? bk : bv);
            unsigned short* dp = (seg == 0) ? Qb : ((seg == 1) ? Kb : Vb);
            const float bval = bp[c];
#pragma unroll
            for (int r = 0; r < 4; r++) {
                const int row = m0 + wr + mi * 16 + cr + r;
                dp[(long long)row * D_ + c] = f2b(acc[mi][ni][r] + bval);
            }
        }
    }
}

// ---------------------------------------------------------------------------
// Fused split-K reduce (NPART bf16 partials, stride pstride) + bias +
// residual + LayerNorm.
// ---------------------------------------------------------------------------
template <int NPART, int HAS_OUTB>
__global__ __launch_bounds__(256) void ln_red_kernel(
    const unsigned short* __restrict__ p, long long pstride,
    const float* __restrict__ resid, const float* __restrict__ bias,
    const float* __restrict__ g, const float* __restrict__ b,
    float* __restrict__ out_f, unsigned short* __restrict__ out_b)
{
    __shared__ float red[8];
    const long long row = blockIdx.x;
    const int tid = threadIdx.x;
    const float4 rv = ((const float4*)(resid + row * D_))[tid];
    const float4 bi = ((const float4*)bias)[tid];
    float v0 = bi.x + rv.x, v1 = bi.y + rv.y, v2 = bi.z + rv.z, v3 = bi.w + rv.w;
#pragma unroll
    for (int k = 0; k < NPART; k++) {
        const ushort4 a = ((const ushort4*)(p + k * pstride + row * D_))[tid];
        v0 += b2f(a.x); v1 += b2f(a.y); v2 += b2f(a.z); v3 += b2f(a.w);
    }

    float s = v0 + v1 + v2 + v3;
#pragma unroll
    for (int o = 32; o > 0; o >>= 1) s += __shfl_xor(s, o);
    if ((tid & 63) == 0) red[tid >> 6] = s;
    __syncthreads();
    const float mean = (red[0] + red[1] + red[2] + red[3]) * (1.0f / D_);

    const float d0 = v0 - mean, d1 = v1 - mean, d2 = v2 - mean, d3 = v3 - mean;
    float q = d0 * d0 + d1 * d1 + d2 * d2 + d3 * d3;
#pragma unroll
    for (int o = 32; o > 0; o >>= 1) q += __shfl_xor(q, o);
    if ((tid & 63) == 0) red[4 + (tid >> 6)] = q;
    __syncthreads();
    const float var = (red[4] + red[5] + red[6] + red[7]) * (1.0f / D_);
    const float inv = rsqrtf(var + 1e-6f);

    const float4 gv = ((const float4*)g)[tid];
    const float4 bv = ((const float4*)b)[tid];
    const float o0 = d0 * inv * gv.x + bv.x;
    const float o1 = d1 * inv * gv.y + bv.y;
    const float o2 = d2 * inv * gv.z + bv.z;
    const float o3 = d3 * inv * gv.w + bv.w;

    ((float4*)(out_f + row * D_))[tid] = float4{o0, o1, o2, o3};
    if (HAS_OUTB) {
        ushort4 u; u.x = f2b(o0); u.y = f2b(o1); u.z = f2b(o2); u.w = f2b(o3);
        ((ushort4*)(out_b + row * D_))[tid] = u;
    }
}

// ---------------------------------------------------------------------------
// softmax over rows of bf16 scores [B*S, S] + fp32 intensity -> bf16 attn
// ---------------------------------------------------------------------------
__global__ __launch_bounds__(256) void softmax_bias_kernel(
    const unsigned short* __restrict__ scores, const float* __restrict__ intensity,
    unsigned short* __restrict__ attn)
{
    __shared__ float red[8];
    const long long row = blockIdx.x;
    const int tid = threadIdx.x;
    const ushort4* s4 = (const ushort4*)(scores + row * S_);
    const float4* i4 = (const float4*)(intensity + row * S_);
    ushort4* dst = (ushort4*)(attn + row * S_);

    float vv[8];
    {
        ushort4 a = s4[tid], b = s4[tid + 256];
        vv[0] = b2f(a.x); vv[1] = b2f(a.y); vv[2] = b2f(a.z); vv[3] = b2f(a.w);
        vv[4] = b2f(b.x); vv[5] = b2f(b.y); vv[6] = b2f(b.z); vv[7] = b2f(b.w);
    }

    float mx = vv[0];
#pragma unroll
    for (int i = 1; i < 8; i++) mx = fmaxf(mx, vv[i]);
#pragma unroll
    for (int o = 32; o > 0; o >>= 1) mx = fmaxf(mx, __shfl_xor(mx, o));
    if ((tid & 63) == 0) red[tid >> 6] = mx;
    __syncthreads();
    mx = fmaxf(fmaxf(red[0], red[1]), fmaxf(red[2], red[3]));

    float e[8];
    float sum = 0.f;
#pragma unroll
    for (int i = 0; i < 8; i++) { e[i] = __expf(vv[i] - mx); sum += e[i]; }
#pragma unroll
    for (int o = 32; o > 0; o >>= 1) sum += __shfl_xor(sum, o);
    if ((tid & 63) == 0) red[4 + (tid >> 6)] = sum;
    __syncthreads();
    sum = red[4] + red[5] + red[6] + red[7];
    const float rs = 1.0f / sum;

#pragma unroll
    for (int i = 0; i < 2; i++) {
        float4 iv = i4[tid + 256 * i];
        ushort4 o;
        o.x = f2b(e[4 * i + 0] * rs + iv.x);
        o.y = f2b(e[4 * i + 1] * rs + iv.y);
        o.z = f2b(e[4 * i + 2] * rs + iv.z);
        o.w = f2b(e[4 * i + 3] * rs + iv.w);
        dst[tid + 256 * i] = o;
    }
}

// ---------------------------------------------------------------------------
extern "C" void kernel_launch(void* const* d_in, const int* in_sizes, int n_in,
                              void* d_out, int out_size, void* d_ws, size_t ws_size,
                              hipStream_t stream)
{
    const float* X   = (const float*)d_in[0];
    const float* inten = (const float*)d_in[1];
    const float* Wq  = (const float*)d_in[2];
    const float* bq  = (const float*)d_in[3];
    const float* Wk  = (const float*)d_in[4];
    const float* bk  = (const float*)d_in[5];
    const float* Wv  = (const float*)d_in[6];
    const float* bv  = (const float*)d_in[7];
    const float* Wo  = (const float*)d_in[8];
    const float* bo  = (const float*)d_in[9];
    const float* W1  = (const float*)d_in[10];
    const float* b1  = (const float*)d_in[11];
    const float* W2  = (const float*)d_in[12];
    const float* b2  = (const float*)d_in[13];
    const float* g1  = (const float*)d_in[14];
    const float* be1 = (const float*)d_in[15];
    const float* g2  = (const float*)d_in[16];
    const float* be2 = (const float*)d_in[17];
    float* out = (float*)d_out;

    char* ws = (char*)d_ws;
    const size_t MB = 1ull << 20;
    // timeline-aliased layout, peak 184 MB:
    unsigned short* Xb   = (unsigned short*)(ws + 0);        // 16MB; dead after QKV
    unsigned short* Wqkv = (unsigned short*)(ws + 16 * MB);  // 6MB
    unsigned short* Wot  = (unsigned short*)(ws + 22 * MB);  // 2MB
    unsigned short* W1t  = (unsigned short*)(ws + 24 * MB);  // 8MB
    unsigned short* W2t  = (unsigned short*)(ws + 32 * MB);  // 8MB
    unsigned short* Qb   = (unsigned short*)(ws + 40 * MB);  // 16MB; dead after scores
    unsigned short* Kb   = (unsigned short*)(ws + 56 * MB);  // 16MB; dead after scores
    unsigned short* Vt   = (unsigned short*)(ws + 72 * MB);  // 16MB; dead after AV
    unsigned short* Sc   = (unsigned short*)(ws + 88 * MB);  // 32MB bf16; dead after softmax
    unsigned short* Vb   = (unsigned short*)(ws + 152 * MB); // 16MB; dead after vtrans
    unsigned short* At   = (unsigned short*)(ws + 152 * MB); // 32MB; dead after AV
    unsigned short* AVp  = (unsigned short*)(ws + 88 * MB);  // 2x16MB bf16 (reuse Sc)
    unsigned short* Op   = (unsigned short*)(ws + 120 * MB); // 4x16MB bf16 (reuse Sc hi + At)
    float*          Hf   = (float*)(ws + 40 * MB);           // 32MB (reuse Qb+Kb)
    unsigned short* Hb   = (unsigned short*)(ws + 72 * MB);  // 16MB (reuse Vt)
    unsigned short* F1   = (unsigned short*)(ws + 88 * MB);  // 64MB (reuse AVp + Op lo)
    unsigned short* Fp   = (unsigned short*)(ws + 152 * MB); // 2x16MB bf16 (reuse Op hi)

    const dim3 blk(256);
    const dim3 blk512(512);
    const long long MN_d = (long long)B_ * S_ * D_;

    // input cast + all weight transposes (2 launches)
    cast_bf16_kernel<<<dim3(8192), blk, 0, stream>>>(
        (const float4*)X, (ushort4*)Xb, B_ * S_ * D_ / 4);
    transpose_all_kernel<<<dim3(12288), blk, 0, stream>>>(
        Wq, Wk, Wv, Wo, W1, W2, Wqkv, Wot, W1t, W2t);

    // fused QKV: 768 blocks x 8 waves; all outputs coalesced
    gemm_qkv<<<dim3(24, 32), blk512, 0, stream>>>(Xb, Wqkv, Qb, Kb, Vb, bq, bk, bv);

    // Vt[b][d][s] = transpose(Vb[b][s][d])
    vtrans_kernel<<<dim3(D_ / 64, S_ / 64, B_), blk, 0, stream>>>(Vb, Vt);

    // scores = Q @ K^T / 32 -> bf16, 512 blocks
    gemm_bt<1, 0, 0><<<dim3(16, 8, 4), blk512, 0, stream>>>(
        Qb, Kb, Sc, nullptr, S_, S_, D_, 0.03125f,
        (long long)S_ * D_, (long long)S_ * D_, (long long)S_ * S_);

    // attn = softmax(scores) + intensity  (bf16)
    softmax_bias_kernel<<<dim3(B_ * S_), blk, 0, stream>>>(Sc, inten, At);

    // AV split-K=2: bf16 partials AVp[part][8192][1024], 512 blocks
    gemm_bt_sk<2><<<dim3(8, 8, 8), blk512, 0, stream>>>(
        At, Vt, AVp, S_, D_, S_ / 2, S_, S_,
        (long long)S_ * S_, (long long)D_ * S_);

    // O-proj: O = (P0+P1) @ Wo^T via linearity -> 4-way split
    // z: ks = z%2 (K-slice), b = z/2 (AV partial); 1024 blocks
    gemm_bt_sk<2><<<dim3(8, 32, 4), blk512, 0, stream>>>(
        AVp, Wot, Op, B_ * S_, D_, D_ / 2, D_, D_, MN_d, 0);

    // h = LN(sum(Op[0..3]) + bo + X) -> Hf fp32 + Hb bf16
    ln_red_kernel<4, 1><<<dim3(B_ * S_), blk, 0, stream>>>(
        Op, MN_d, X, bo, g1, be1, Hf, Hb);

    // F1 = leaky_relu(h @ W1 + b1)  (bf16), 1024 blocks
    gemm_bt<1, 1, 1><<<dim3(32, 32), blk512, 0, stream>>>(
        Hb, W1t, F1, b1, B_ * S_, DFF_, D_, 1.0f, 0, 0, 0);

    // ffn2 split-K=2: bf16 partials, 512 blocks
    gemm_bt_sk<2><<<dim3(8, 32, 2), blk512, 0, stream>>>(
        F1, W2t, Fp, B_ * S_, D_, DFF_ / 2, DFF_, DFF_, 0, 0);

    // out = LN(Fp0 + Fp1 + b2 + h)
    ln_red_kernel<2, 0><<<dim3(B_ * S_), blk, 0, stream>>>(
        Fp, MN_d, Hf, b2, g2, be2, out, nullptr);
}